// Round 14
// baseline (232.219 us; speedup 1.0000x reference)
//
#include <hip/hip_runtime.h>
#include <stdint.h>

typedef unsigned short ushort_t;
typedef unsigned char uchar_t;
typedef __attribute__((ext_vector_type(8))) short short8;   // 8 bf16 = 4 VGPRs
typedef __attribute__((ext_vector_type(4))) float float4v;  // MFMA acc
typedef __attribute__((ext_vector_type(2))) float float2v;  // packed f32 pair

#define N_NODES 100000
#define N_EDGES 1600000
#define D 128
#define NB_GEMM 1563   // (N_NODES+63)/64 tiles of 64 rows
#define NBG     521    // gemm blocks: tiles b, b+521, b+1042 (521*3 = 1563)
#define NWIN    125    // edge windows (b1 blocks)
#define EPB     12800  // edges per window: 125*12800 = 1,600,000 = 50*256 each
#define NBUCK   1563   // ceil(100000/64), 64 nodes per bucket
#define CAP     1280   // per-bucket edge cap (mean 1024, sd 32 -> 8 sigma)

static __device__ __forceinline__ float2v up2(uint32_t u) {  // 2 bf16 -> 2 f32
    float2v r;
    r.x = __builtin_bit_cast(float, u << 16);
    r.y = __builtin_bit_cast(float, u & 0xffff0000u);
    return r;
}
static __device__ __forceinline__ uint32_t f2bf_u(float f) {
    uint32_t u = __builtin_bit_cast(uint32_t, f);
    return (u + 0x7fffu + ((u >> 16) & 1u)) >> 16;           // RNE
}
static __device__ __forceinline__ ushort_t f2bf(float f) {
    return (ushort_t)f2bf_u(f);
}
static __device__ __forceinline__ uint32_t pack2(float a, float b) {
    return f2bf_u(a) | (f2bf_u(b) << 16);
}
// leaky_relu(0.2) -> clip(-2,2) -> exp
static __device__ __forceinline__ float edge_e(float s) {
    float x = (s >= 0.0f) ? s : 0.2f * s;
    x = fminf(fmaxf(x, -2.0f), 2.0f);
    return __expf(x);
}

// ---------------- fused: [0..520] gemm (3 tiles, self-staged W+wa, prefetch) -
//                  [521..645] b1 bucket sort: 12800 edges -> 1563 buckets -----
// H row layout is PACKED-PAIR order: element l16*8+2j+hi <-> col (2j+hi)*16+l16.
__global__ void __launch_bounds__(256) fused_kernel(const float* __restrict__ X,
                                                    const float* __restrict__ W,
                                                    const float* __restrict__ KA,
                                                    ushort_t* __restrict__ H,
                                                    float* __restrict__ st,
                                                    float* __restrict__ ss,
                                                    int M,
                                                    const int* __restrict__ E,
                                                    int* __restrict__ sortedE,
                                                    uchar_t* __restrict__ bmat,
                                                    ushort_t* __restrict__ lofs) {
    __shared__ __align__(16) ushort_t lds_raw[16384];   // 32 KB, both branches
    __shared__ float lds_wa[256];                       // gemm: W @ ka (exact)
    __shared__ int   ldet;                              // b1: dtype verdict
    int tid = threadIdx.x;
    if (blockIdx.x >= NBG) {
        // ------------- b1: two-pass bucket sort by tgt>>6, LDS atomics only -
        int eb = blockIdx.x - NBG;
        int* lhist = (int*)lds_raw;                 // [2048] (1563 used)
        int* lpart = ((int*)lds_raw) + 2048;        // [256]
        int t = tid;
        // self-detect edge dtype from first 2048 edges (identical all blocks)
        if (t == 0) ldet = 0;
        for (int j = t; j < 2048; j += 256) lhist[j] = 0;
        __syncthreads();
        int nz = 0;
#pragma unroll
        for (int j = 0; j < 8; j++)
            if (E[(t + j * 256) * 2 + 1] != 0) nz = 1;
        if (nz) atomicOr(&ldet, 1);
        __syncthreads();
        int i64 = (ldet == 0) ? 1 : 0;              // block-uniform
        int base = eb * EPB;
        // pass 1: count buckets (50*256 = 12800 = EPB exactly)
        for (int j = 0; j < 50; j++) {
            int i = base + j * 256 + t;
            int tgt = i64 ? E[(size_t)i * 4] : E[(size_t)i * 2];
            if ((unsigned)tgt >= (unsigned)N_NODES) tgt = 0;
            atomicAdd(&lhist[tgt >> 6], 1);
        }
        __syncthreads();
        // per-thread 8 bins -> block scan
        int c[8], sum = 0;
#pragma unroll
        for (int k = 0; k < 8; k++) { c[k] = lhist[t * 8 + k]; sum += c[k]; }
        lpart[t] = sum;
        __syncthreads();
        for (int off = 1; off < 256; off <<= 1) {   // Hillis-Steele inclusive
            int x = (t >= off) ? lpart[t - off] : 0;
            __syncthreads();
            lpart[t] += x;
            __syncthreads();
        }
        int e = lpart[t] - sum;                     // exclusive base of bin 8t
        int ee[8];
#pragma unroll
        for (int k = 0; k < 8; k++) { ee[k] = e; e += c[k]; }
#pragma unroll
        for (int k = 0; k < 8; k++) {
            int bb = t * 8 + k;
            if (bb < NBUCK) {
                bmat[eb * NBUCK + bb] = (uchar_t)c[k];   // mean 8.2, u8 safe
                lofs[eb * NBUCK + bb] = (ushort_t)ee[k]; // < 12800, u16 safe
            }
        }
        // lhist becomes the placement cursor (own slots, no cross-thread reads)
#pragma unroll
        for (int k = 0; k < 8; k++) lhist[t * 8 + k] = ee[k];
        __syncthreads();
        // pass 2: re-read E, place packed (tgt_local<<17)|src into window
        for (int j = 0; j < 50; j++) {
            int i = base + j * 256 + t;
            int tgt, src;
            if (i64) { uint4 v = *(const uint4*)(E + (size_t)i * 4); tgt = (int)v.x; src = (int)v.z; }
            else     { uint2 v = *(const uint2*)(E + (size_t)i * 2); tgt = (int)v.x; src = (int)v.y; }
            if ((unsigned)tgt >= (unsigned)N_NODES) tgt = 0;
            if ((unsigned)src >= (unsigned)N_NODES) src = 0;
            int pos = atomicAdd(&lhist[tgt >> 6], 1);
            if (pos < EPB) sortedE[base + pos] = ((tgt & 63) << 17) | src;
        }
        return;
    }
    // -------- gemm branch: self-stage W -> fragment-order bf16 LDS + wa -----
    {
        const float4* W4 = (const float4*)W;        // 4096 x 16B, L2-hot
        for (int c = tid; c < 4096; c += 256) {
            float4 w4 = W4[c];
            int i0 = c * 4;                         // 4 elems, same row k
            int k = i0 >> 7;
            int kb = k >> 5, q = (k >> 3) & 3, jj = k & 7;
            const float* wp = (const float*)&w4;
#pragma unroll
            for (int u = 0; u < 4; u++) {
                int nn = (i0 + u) & 127;
                int tt = nn >> 4, l = nn & 15;
                lds_raw[((kb * 8 + tt) * 64 + q * 16 + l) * 8 + jj] = f2bf(wp[u]);
            }
        }
        // wa[half*128+k] = dot(W row k, KA col half) -- fp32, float4 loads
        int half = tid >> 7, k = tid & 127;
        const float4* kav4  = (const float4*)(KA + half * 128);
        const float4* wrow4 = (const float4*)(W + (size_t)k * 128);
        float acc = 0.0f;
#pragma unroll 8
        for (int j = 0; j < 32; j++) {
            float4 a4 = wrow4[j], b4 = kav4[j];
            acc += a4.x * b4.x + a4.y * b4.y + a4.z * b4.z + a4.w * b4.w;
        }
        lds_wa[half * 128 + k] = acc;
    }
    __syncthreads();

    int wave = tid >> 6, lane = tid & 63;
    int quad = lane >> 4, l16 = lane & 15;
    int t0 = blockIdx.x;

    float4 f[8];                                    // current tile X (A rows)
    {
        int ar = t0 * 64 + wave * 16 + l16; if (ar >= M) ar = M - 1;
        const float* xr = X + (size_t)ar * D + quad * 8;
#pragma unroll
        for (int kb = 0; kb < 4; kb++) {
            f[kb * 2]     = *(const float4*)(xr + kb * 32);
            f[kb * 2 + 1] = *(const float4*)(xr + kb * 32 + 4);
        }
    }
#pragma unroll
    for (int it = 0; it < 3; it++) {                // tiles t0, t0+521, t0+1042
        int m0 = (t0 + it * NBG) * 64 + wave * 16;
        float4 nf[8];
        if (it < 2) {                               // prefetch next tile's X
            int ar = (t0 + (it + 1) * NBG) * 64 + wave * 16 + l16;
            if (ar >= M) ar = M - 1;
            const float* xr = X + (size_t)ar * D + quad * 8;
#pragma unroll
            for (int kb = 0; kb < 4; kb++) {
                nf[kb * 2]     = *(const float4*)(xr + kb * 32);
                nf[kb * 2 + 1] = *(const float4*)(xr + kb * 32 + 4);
            }
        }
        // fused scores (fp32) + bf16 cvt
        short8 a[4];
        float sct = 0.0f, scs = 0.0f;
#pragma unroll
        for (int kb = 0; kb < 4; kb++) {            // A[m=l16][k=kb*32+quad*8+j]
            float4 f0 = f[kb * 2], f1 = f[kb * 2 + 1];
            const float* wt0 = lds_wa + kb * 32 + quad * 8;
            float4 t0v = *(const float4*)(wt0);
            float4 t1v = *(const float4*)(wt0 + 4);
            float4 s0v = *(const float4*)(wt0 + 128);
            float4 s1v = *(const float4*)(wt0 + 132);
            sct += f0.x * t0v.x + f0.y * t0v.y + f0.z * t0v.z + f0.w * t0v.w
                 + f1.x * t1v.x + f1.y * t1v.y + f1.z * t1v.z + f1.w * t1v.w;
            scs += f0.x * s0v.x + f0.y * s0v.y + f0.z * s0v.z + f0.w * s0v.w
                 + f1.x * s1v.x + f1.y * s1v.y + f1.z * s1v.z + f1.w * s1v.w;
            short8 v;
            v[0] = (short)f2bf(f0.x); v[1] = (short)f2bf(f0.y);
            v[2] = (short)f2bf(f0.z); v[3] = (short)f2bf(f0.w);
            v[4] = (short)f2bf(f1.x); v[5] = (short)f2bf(f1.y);
            v[6] = (short)f2bf(f1.z); v[7] = (short)f2bf(f1.w);
            a[kb] = v;
        }
        sct += __shfl_xor(sct, 16); sct += __shfl_xor(sct, 32);
        scs += __shfl_xor(scs, 16); scs += __shfl_xor(scs, 32);
        if (quad == 0 && m0 + l16 < M) { st[m0 + l16] = sct; ss[m0 + l16] = scs; }

        float4v acc[8] = {};
#pragma unroll
        for (int kb = 0; kb < 4; kb++) {
#pragma unroll
            for (int t = 0; t < 8; t++) {           // B[k=kb*32+quad*8+j][n=t*16+l16]
                short8 b = *(const short8*)(&lds_raw[((kb * 8 + t) * 64 + lane) * 8]);
                acc[t] = __builtin_amdgcn_mfma_f32_16x16x32_bf16(a[kb], b, acc[t], 0, 0, 0);
            }
        }
        // C/D: col = t*16 + l16, row = quad*4 + r   [m89-verified]
#pragma unroll
        for (int r = 0; r < 4; r++) {
            int orow = m0 + quad * 4 + r;
            if (orow < M) {
                uint4 v;
                v.x = pack2(acc[0][r], acc[1][r]);
                v.y = pack2(acc[2][r], acc[3][r]);
                v.z = pack2(acc[4][r], acc[5][r]);
                v.w = pack2(acc[6][r], acc[7][r]);
                *(uint4*)(H + (size_t)orow * D + l16 * 8) = v;
            }
        }
        if (it < 2) {
#pragma unroll
            for (int j = 0; j < 8; j++) f[j] = nf[j];
        }
    }
}

// ---------------- agg2: fused CSR-build + aggregation, 1 block = 64 nodes ----
// Grid 1563 x 512 threads = 12504 waves -> machine fills; Phase A once/edge.
__global__ void __launch_bounds__(512) agg2_kernel(const uchar_t* __restrict__ bmat,
                                                   const ushort_t* __restrict__ lofs,
                                                   const int* __restrict__ sortedE,
                                                   const float* __restrict__ st,
                                                   const float* __restrict__ ss,
                                                   const ushort_t* __restrict__ H,
                                                   float* __restrict__ out) {
    __shared__ int stage[CAP];
    __shared__ int sortedLoc[CAP];
    __shared__ int lh[64];
    __shared__ int lrp[65];
    __shared__ int wsum[8];
    __shared__ int lsoff[NWIN];
    __shared__ int lsst[NWIN];
    int b = blockIdx.x, t = threadIdx.x;
    int lane = t & 63, wv = t >> 6;
    // ---- Phase A1: exclusive scan of 125 window counts (shfl) --------------
    int cnt = 0, sst = 0;
    if (t < NWIN) {
        cnt = bmat[t * NBUCK + b];
        sst = lofs[t * NBUCK + b];
    }
    int x = cnt;
#pragma unroll
    for (int off = 1; off < 64; off <<= 1) {        // wave inclusive scan
        int y = __shfl_up(x, off);
        if (lane >= off) x += y;
    }
    if (lane == 63) wsum[wv] = x;                   // waves 2-7 write 0
    if (t < 64) lh[t] = 0;
    __syncthreads();
    int wbase = 0, total = 0;
#pragma unroll
    for (int w = 0; w < 8; w++) {
        int sv = wsum[w];
        if (w < wv) wbase += sv;
        total += sv;
    }
    if (total > CAP) total = CAP;                   // 8-sigma guard
    int soff = wbase + x - cnt;                     // staging offset (exclusive)
    if (t < NWIN) { lsoff[t] = soff; lsst[t] = sst; }
    __syncthreads();
    // ---- flat coalesced gather: thread j pulls stage[j] --------------------
    for (int j = t; j < total; j += 512) {
        int lo = 0, hi = NWIN - 1;                  // largest w: lsoff[w] <= j
        while (lo < hi) {
            int mid = (lo + hi + 1) >> 1;
            if (lsoff[mid] <= j) lo = mid; else hi = mid - 1;
        }
        stage[j] = sortedE[lo * EPB + lsst[lo] + (j - lsoff[lo])];
    }
    __syncthreads();
    // ---- Phase A2: histogram over 64 local nodes ---------------------------
    for (int j = t; j < total; j += 512)
        atomicAdd(&lh[stage[j] >> 17], 1);
    __syncthreads();
    // ---- Phase A3: scan 64-bin hist -> local rowp (wave 0 shfl) ------------
    if (t < 64) {
        int v = lh[t];
        int xs = v;
#pragma unroll
        for (int off = 1; off < 64; off <<= 1) {
            int y = __shfl_up(xs, off);
            if (lane >= off) xs += y;
        }
        int ex = xs - v;
        lrp[t] = ex;
        lh[t]  = ex;                                // placement cursor
    }
    if (t == 0) lrp[64] = total;
    __syncthreads();
    for (int j = t; j < total; j += 512) {          // place sorted-by-node
        int p = stage[j];
        int pos = atomicAdd(&lh[p >> 17], 1);
        if (pos < total) sortedLoc[pos] = p & 0x1FFFF;
    }
    __syncthreads();
    // ---------------- Phase B: aggregate from LDS-sorted edges --------------
    int g = lane >> 4, l = lane & 15;
    for (int nd = wv; nd < 64; nd += 8) {
        int gnode = b * 64 + nd;
        if (gnode >= N_NODES) break;                // only bucket 1562 tail
        int start = lrp[nd], end = lrp[nd + 1];
        float stn = st[gnode];
        float den = 0.0f;
        float2v acc2[4] = {};
        int m = start + g;
        for (; m + 12 < end; m += 16) {             // 4 chains in flight/group
            int s0 = sortedLoc[m],     s1 = sortedLoc[m + 4];
            int s2 = sortedLoc[m + 8], s3 = sortedLoc[m + 12];
            float e0 = edge_e(stn + ss[s0]);
            float e1 = edge_e(stn + ss[s1]);
            float e2 = edge_e(stn + ss[s2]);
            float e3 = edge_e(stn + ss[s3]);
            den += (e0 + e1) + (e2 + e3);
            uint4 p0 = *(const uint4*)(H + ((unsigned)s0 << 7) + l * 8);
            uint4 p1 = *(const uint4*)(H + ((unsigned)s1 << 7) + l * 8);
            uint4 p2 = *(const uint4*)(H + ((unsigned)s2 << 7) + l * 8);
            uint4 p3 = *(const uint4*)(H + ((unsigned)s3 << 7) + l * 8);
            float2v E0 = {e0, e0}, E1 = {e1, e1}, E2 = {e2, e2}, E3 = {e3, e3};
            acc2[0] += E0 * up2(p0.x) + E1 * up2(p1.x) + E2 * up2(p2.x) + E3 * up2(p3.x);
            acc2[1] += E0 * up2(p0.y) + E1 * up2(p1.y) + E2 * up2(p2.y) + E3 * up2(p3.y);
            acc2[2] += E0 * up2(p0.z) + E1 * up2(p1.z) + E2 * up2(p2.z) + E3 * up2(p3.z);
            acc2[3] += E0 * up2(p0.w) + E1 * up2(p1.w) + E2 * up2(p2.w) + E3 * up2(p3.w);
        }
        for (; m + 4 < end; m += 8) {               // 2-chain remainder
            int s0 = sortedLoc[m], s1 = sortedLoc[m + 4];
            float e0 = edge_e(stn + ss[s0]);
            float e1 = edge_e(stn + ss[s1]);
            den += e0 + e1;
            uint4 p0 = *(const uint4*)(H + ((unsigned)s0 << 7) + l * 8);
            uint4 p1 = *(const uint4*)(H + ((unsigned)s1 << 7) + l * 8);
            float2v E0 = {e0, e0}, E1 = {e1, e1};
            acc2[0] += E0 * up2(p0.x) + E1 * up2(p1.x);
            acc2[1] += E0 * up2(p0.y) + E1 * up2(p1.y);
            acc2[2] += E0 * up2(p0.z) + E1 * up2(p1.z);
            acc2[3] += E0 * up2(p0.w) + E1 * up2(p1.w);
        }
        if (m < end) {
            int s0 = sortedLoc[m];
            float e0 = edge_e(stn + ss[s0]);
            den += e0;
            uint4 p0 = *(const uint4*)(H + ((unsigned)s0 << 7) + l * 8);
            float2v E0 = {e0, e0};
            acc2[0] += E0 * up2(p0.x);
            acc2[1] += E0 * up2(p0.y);
            acc2[2] += E0 * up2(p0.z);
            acc2[3] += E0 * up2(p0.w);
        }
        den += __shfl_xor(den, 16);
        den += __shfl_xor(den, 32);
        float r[8];
#pragma unroll
        for (int j = 0; j < 4; j++) {
            float a0 = acc2[j].x, a1 = acc2[j].y;
            a0 += __shfl_xor(a0, 16); a0 += __shfl_xor(a0, 32);
            a1 += __shfl_xor(a1, 16); a1 += __shfl_xor(a1, 32);
            r[j * 2] = a0; r[j * 2 + 1] = a1;
        }
        float inv = 1.0f / (den + 1e-9f);
        if (g == 0) {
            // packed-pair H layout: r[k] holds logical col k*16 + l.
#pragma unroll
            for (int k = 0; k < 8; k++)
                out[(size_t)gnode * D + k * 16 + l] = r[k] * inv;
        }
    }
}

extern "C" void kernel_launch(void* const* d_in, const int* in_sizes, int n_in,
                              void* d_out, int out_size, void* d_ws, size_t ws_size,
                              hipStream_t stream) {
    const float* X  = (const float*)d_in[0];
    const int*   E  = (const int*)d_in[1];
    const float* W  = (const float*)d_in[2];
    const float* KA = (const float*)d_in[3];
    for (int i = 0; i < n_in; i++) {
        int s = in_sizes[i];
        if (s == N_NODES * D)      X  = (const float*)d_in[i];
        else if (s == N_EDGES * 2) E  = (const int*)d_in[i];
        else if (s == D * D)       W  = (const float*)d_in[i];
        else if (s == 2 * D)       KA = (const float*)d_in[i];
    }
    float* out = (float*)d_out;                // fp32 [100000,128]; no aliasing

    char* ws = (char*)d_ws;
    // workspace layout (aligned), total 33,386,128 B (< proven 33.64 MB)
    ushort_t* H        = (ushort_t*)(ws + 0);           // 25,600,000 B (bf16 h)
    float*    st       = (float*)   (ws + 25600000);    //    400,000 B
    float*    ssb      = (float*)   (ws + 26000000);    //    400,000 B
    int*      sortedE  = (int*)     (ws + 26400000);    //  6,400,000 B
    ushort_t* lofs     = (ushort_t*)(ws + 32800000);    //    390,752 B (u16)
    uchar_t*  bmat     = (uchar_t*) (ws + 33190752);    //    195,375 B (u8)

    fused_kernel<<<NBG + NWIN, 256, 0, stream>>>(X, W, KA, H, st, ssb,
                                                 N_NODES, E,
                                                 sortedE, bmat, lofs);
    agg2_kernel<<<NBUCK, 512, 0, stream>>>(bmat, lofs, sortedE, st, ssb,
                                           H, out);
}

// Round 15
// 227.171 us; speedup vs baseline: 1.0222x; 1.0222x over previous
//
#include <hip/hip_runtime.h>
#include <stdint.h>

typedef unsigned short ushort_t;
typedef __attribute__((ext_vector_type(8))) short short8;   // 8 bf16 = 4 VGPRs
typedef __attribute__((ext_vector_type(4))) float float4v;  // MFMA acc
typedef __attribute__((ext_vector_type(2))) float float2v;  // packed f32 pair

#define N_NODES 100000
#define N_EDGES 1600000
#define D 128
#define NB_GEMM 1563   // (N_NODES+63)/64 tiles of 64 rows, 1 block each
#define NWIN    250    // edge windows (b1 blocks)
#define EPB     6400   // edges per window: 250*6400 = 1,600,000 = 25*256 each
#define BUCKETS 782    // ceil(100000/128), 128 nodes per bucket
#define CAP     2560   // per-bucket edge cap (mean 2046, sd 45 -> 11 sigma)

static __device__ __forceinline__ float2v up2(uint32_t u) {  // 2 bf16 -> 2 f32
    float2v r;
    r.x = __builtin_bit_cast(float, u << 16);
    r.y = __builtin_bit_cast(float, u & 0xffff0000u);
    return r;
}
static __device__ __forceinline__ uint32_t f2bf_u(float f) {
    uint32_t u = __builtin_bit_cast(uint32_t, f);
    return (u + 0x7fffu + ((u >> 16) & 1u)) >> 16;           // RNE
}
static __device__ __forceinline__ ushort_t f2bf(float f) {
    return (ushort_t)f2bf_u(f);
}
static __device__ __forceinline__ uint32_t pack2(float a, float b) {
    return f2bf_u(a) | (f2bf_u(b) << 16);
}
// leaky_relu(0.2) -> clip(-2,2) -> exp
static __device__ __forceinline__ float edge_e(float s) {
    float x = (s >= 0.0f) ? s : 0.2f * s;
    x = fminf(fmaxf(x, -2.0f), 2.0f);
    return __expf(x);
}

// ---------------- fused: [0..1562] gemm 1 tile/block (self-staged W+wa) ------
//                  [1563..1812] b1 bucket sort (reg-cached, 1 E read) ---------
// H row layout is PACKED-PAIR order: element l16*8+2j+hi <-> col (2j+hi)*16+l16.
__global__ void __launch_bounds__(256) fused_kernel(const float* __restrict__ X,
                                                    const float* __restrict__ W,
                                                    const float* __restrict__ KA,
                                                    ushort_t* __restrict__ H,
                                                    float* __restrict__ st,
                                                    float* __restrict__ ss,
                                                    int M,
                                                    const int* __restrict__ E,
                                                    int* __restrict__ sortedE,
                                                    ushort_t* __restrict__ bmat,
                                                    ushort_t* __restrict__ lofs) {
    __shared__ __align__(16) ushort_t lds_raw[16384];   // 32 KB, both branches
    __shared__ float lds_wa[256];                       // gemm: W @ ka (exact)
    __shared__ int   ldet;                              // b1: dtype verdict
    int tid = threadIdx.x;
    if (blockIdx.x >= NB_GEMM) {
        // ------------- b1: bucket-sort 6400 edges by tgt>>7, LDS atomics only
        int eb = blockIdx.x - NB_GEMM;
        int* lhist = (int*)lds_raw;                 // [1024] (782 used)
        int* lpart = ((int*)lds_raw) + 1024;        // [256]
        int t = tid;
        // self-detect edge dtype from first 2048 edges (identical all blocks)
        if (t == 0) ldet = 0;
        for (int j = t; j < 1024; j += 256) lhist[j] = 0;
        __syncthreads();
        int nz = 0;
#pragma unroll
        for (int j = 0; j < 8; j++)
            if (E[(t + j * 256) * 2 + 1] != 0) nz = 1;
        if (nz) atomicOr(&ldet, 1);
        __syncthreads();
        int i64 = (ldet == 0) ? 1 : 0;              // block-uniform
        int base = eb * EPB;
        int bin[25], w[25];                         // static-indexed (unrolled)
#pragma unroll
        for (int j = 0; j < 25; j++) {
            int i = base + j * 256 + t;
            int tgt, src;
            if (i64) { uint4 v = *(const uint4*)(E + (size_t)i * 4); tgt = (int)v.x; src = (int)v.z; }
            else     { uint2 v = *(const uint2*)(E + (size_t)i * 2); tgt = (int)v.x; src = (int)v.y; }
            if ((unsigned)tgt >= (unsigned)N_NODES) tgt = 0;
            if ((unsigned)src >= (unsigned)N_NODES) src = 0;
            bin[j] = tgt >> 7;
            w[j]   = ((tgt & 127) << 17) | src;
            atomicAdd(&lhist[bin[j]], 1);
        }
        __syncthreads();
        // per-thread 4 bins -> block scan
        int c0 = lhist[t * 4], c1 = lhist[t * 4 + 1];
        int c2 = lhist[t * 4 + 2], c3 = lhist[t * 4 + 3];
        int sum = c0 + c1 + c2 + c3;
        lpart[t] = sum;
        __syncthreads();
        for (int off = 1; off < 256; off <<= 1) {   // Hillis-Steele inclusive
            int x = (t >= off) ? lpart[t - off] : 0;
            __syncthreads();
            lpart[t] += x;
            __syncthreads();
        }
        int e0 = lpart[t] - sum;                    // exclusive base of bin 4t
        int e1 = e0 + c0, e2 = e1 + c1, e3 = e2 + c2;
        int cc[4] = {c0, c1, c2, c3};
        int ee[4] = {e0, e1, e2, e3};
#pragma unroll
        for (int k = 0; k < 4; k++) {
            int bb = t * 4 + k;
            if (bb < BUCKETS) {
                bmat[eb * BUCKETS + bb] = (ushort_t)cc[k];
                lofs[eb * BUCKETS + bb] = (ushort_t)ee[k];
            }
        }
        // lhist becomes the placement cursor (own slots, no cross-thread reads)
        lhist[t * 4] = e0; lhist[t * 4 + 1] = e1;
        lhist[t * 4 + 2] = e2; lhist[t * 4 + 3] = e3;
        __syncthreads();
        // pass 2 entirely from registers
#pragma unroll
        for (int j = 0; j < 25; j++) {
            int pos = atomicAdd(&lhist[bin[j]], 1);
            if (pos < EPB) sortedE[base + pos] = w[j];
        }
        return;
    }
    // -------- gemm branch: conflict-free W staging (short8 per thread) ------
    {
        // task c -> (kb,tt,q,l): writes ONE contiguous 16B group (8 consec k)
        for (int c = tid; c < 2048; c += 256) {
            int l = c & 15, q = (c >> 4) & 3, tt = (c >> 6) & 7, kb = c >> 9;
            int n = tt * 16 + l;
            int k0 = kb * 32 + q * 8;
            short8 v;
#pragma unroll
            for (int jj = 0; jj < 8; jj++)
                v[jj] = (short)f2bf(W[(size_t)(k0 + jj) * 128 + n]);
            *(short8*)(&lds_raw[((kb * 8 + tt) * 64 + q * 16 + l) * 8]) = v;
        }
        // wa[half*128+k] = dot(W row k, KA col half) -- fp32, float4 loads
        int half = tid >> 7, k = tid & 127;
        const float4* kav4  = (const float4*)(KA + half * 128);
        const float4* wrow4 = (const float4*)(W + (size_t)k * 128);
        float acc = 0.0f;
#pragma unroll 8
        for (int j = 0; j < 32; j++) {
            float4 a4 = wrow4[j], b4 = kav4[j];
            acc += a4.x * b4.x + a4.y * b4.y + a4.z * b4.z + a4.w * b4.w;
        }
        lds_wa[half * 128 + k] = acc;
    }
    __syncthreads();

    int wave = tid >> 6, lane = tid & 63;
    int quad = lane >> 4, l16 = lane & 15;
    int m0 = blockIdx.x * 64 + wave * 16;

    // load X rows (A fragments)
    float4 f[8];
    {
        int ar = m0 + l16; if (ar >= M) ar = M - 1;
        const float* xr = X + (size_t)ar * D + quad * 8;
#pragma unroll
        for (int kb = 0; kb < 4; kb++) {
            f[kb * 2]     = *(const float4*)(xr + kb * 32);
            f[kb * 2 + 1] = *(const float4*)(xr + kb * 32 + 4);
        }
    }
    // fused scores (fp32) + bf16 cvt
    short8 a[4];
    float sct = 0.0f, scs = 0.0f;
#pragma unroll
    for (int kb = 0; kb < 4; kb++) {                // A[m=l16][k=kb*32+quad*8+j]
        float4 f0 = f[kb * 2], f1 = f[kb * 2 + 1];
        const float* wt0 = lds_wa + kb * 32 + quad * 8;
        float4 t0v = *(const float4*)(wt0);
        float4 t1v = *(const float4*)(wt0 + 4);
        float4 s0v = *(const float4*)(wt0 + 128);
        float4 s1v = *(const float4*)(wt0 + 132);
        sct += f0.x * t0v.x + f0.y * t0v.y + f0.z * t0v.z + f0.w * t0v.w
             + f1.x * t1v.x + f1.y * t1v.y + f1.z * t1v.z + f1.w * t1v.w;
        scs += f0.x * s0v.x + f0.y * s0v.y + f0.z * s0v.z + f0.w * s0v.w
             + f1.x * s1v.x + f1.y * s1v.y + f1.z * s1v.z + f1.w * s1v.w;
        short8 v;
        v[0] = (short)f2bf(f0.x); v[1] = (short)f2bf(f0.y);
        v[2] = (short)f2bf(f0.z); v[3] = (short)f2bf(f0.w);
        v[4] = (short)f2bf(f1.x); v[5] = (short)f2bf(f1.y);
        v[6] = (short)f2bf(f1.z); v[7] = (short)f2bf(f1.w);
        a[kb] = v;
    }
    sct += __shfl_xor(sct, 16); sct += __shfl_xor(sct, 32);
    scs += __shfl_xor(scs, 16); scs += __shfl_xor(scs, 32);
    if (quad == 0 && m0 + l16 < M) { st[m0 + l16] = sct; ss[m0 + l16] = scs; }

    float4v acc[8] = {};
#pragma unroll
    for (int kb = 0; kb < 4; kb++) {
#pragma unroll
        for (int t = 0; t < 8; t++) {               // B[k=kb*32+quad*8+j][n=t*16+l16]
            short8 b = *(const short8*)(&lds_raw[((kb * 8 + t) * 64 + lane) * 8]);
            acc[t] = __builtin_amdgcn_mfma_f32_16x16x32_bf16(a[kb], b, acc[t], 0, 0, 0);
        }
    }
    // C/D: col = t*16 + l16, row = quad*4 + r   [m89-verified]
#pragma unroll
    for (int r = 0; r < 4; r++) {
        int orow = m0 + quad * 4 + r;
        if (orow < M) {
            uint4 v;
            v.x = pack2(acc[0][r], acc[1][r]);
            v.y = pack2(acc[2][r], acc[3][r]);
            v.z = pack2(acc[4][r], acc[5][r]);
            v.w = pack2(acc[6][r], acc[7][r]);
            *(uint4*)(H + (size_t)orow * D + l16 * 8) = v;
        }
    }
}

// ---------------- agg2: fused CSR-build + aggregation, 1 block = 1 bucket ----
// Phase A: shfl-scan; FLAT coalesced gather via binary search; hist+scan+place.
// Phase B: 8 waves x 16 nodes, 4 edge-slot groups/wave, unroll-4 gather of H.
__global__ void __launch_bounds__(512) agg2_kernel(const ushort_t* __restrict__ bmat,
                                                   const ushort_t* __restrict__ lofs,
                                                   const int* __restrict__ sortedE,
                                                   const float* __restrict__ st,
                                                   const float* __restrict__ ss,
                                                   const ushort_t* __restrict__ H,
                                                   float* __restrict__ out) {
    __shared__ int stage[CAP];
    __shared__ int sortedLoc[CAP];
    __shared__ int lh[128];
    __shared__ int lrp[129];
    __shared__ int wsum[8];
    __shared__ int lsoff[NWIN];
    __shared__ int lsst[NWIN];
    int b = blockIdx.x, t = threadIdx.x;
    int lane = t & 63, wv = t >> 6;
    // ---- Phase A1: exclusive scan of 250 window counts (shfl) --------------
    int cnt = 0, sst = 0;
    if (t < NWIN) {
        cnt = bmat[t * BUCKETS + b];
        sst = lofs[t * BUCKETS + b];
    }
    int x = cnt;
#pragma unroll
    for (int off = 1; off < 64; off <<= 1) {        // wave inclusive scan
        int y = __shfl_up(x, off);
        if (lane >= off) x += y;
    }
    if (lane == 63) wsum[wv] = x;
    if (t < 128) lh[t] = 0;
    __syncthreads();
    int wbase = 0, total = 0;
#pragma unroll
    for (int w = 0; w < 8; w++) {
        int sv = wsum[w];
        if (w < wv) wbase += sv;
        total += sv;
    }
    if (total > CAP) total = CAP;                   // 11-sigma guard
    int soff = wbase + x - cnt;                     // staging offset (exclusive)
    if (t < NWIN) { lsoff[t] = soff; lsst[t] = sst; }
    __syncthreads();
    // ---- flat coalesced gather: thread j pulls stage[j] --------------------
    for (int j = t; j < total; j += 512) {
        int lo = 0, hi = NWIN - 1;                  // largest w: lsoff[w] <= j
        while (lo < hi) {
            int mid = (lo + hi + 1) >> 1;
            if (lsoff[mid] <= j) lo = mid; else hi = mid - 1;
        }
        stage[j] = sortedE[lo * EPB + lsst[lo] + (j - lsoff[lo])];
    }
    __syncthreads();
    // ---- Phase A2: histogram over 128 local nodes --------------------------
    for (int j = t; j < total; j += 512)
        atomicAdd(&lh[stage[j] >> 17], 1);
    __syncthreads();
    // ---- Phase A3: scan hist -> local rowp (shfl over waves 0-1) -----------
    int v = (t < 128) ? lh[t] : 0;
    int xs = v;
#pragma unroll
    for (int off = 1; off < 64; off <<= 1) {
        int y = __shfl_up(xs, off);
        if (lane >= off) xs += y;
    }
    if (t == 63) wsum[0] = xs;                      // wave0 total
    __syncthreads();
    if (t < 128) {
        int inc = (wv == 1) ? xs + wsum[0] : xs;
        int ex = inc - v;
        lrp[t] = ex;
        lh[t]  = ex;                                // placement cursor
    }
    if (t == 0) lrp[128] = total;
    __syncthreads();
    for (int j = t; j < total; j += 512) {          // place sorted-by-node
        int p = stage[j];
        int pos = atomicAdd(&lh[p >> 17], 1);
        if (pos < total) sortedLoc[pos] = p & 0x1FFFF;
    }
    __syncthreads();
    // ---------------- Phase B: aggregate from LDS-sorted edges --------------
    int g = lane >> 4, l = lane & 15;
    for (int nd = wv; nd < 128; nd += 8) {
        int gnode = b * 128 + nd;
        if (gnode >= N_NODES) break;                // only bucket 781 tail
        int start = lrp[nd], end = lrp[nd + 1];
        float stn = st[gnode];
        float den = 0.0f;
        float2v acc2[4] = {};
        int m = start + g;
        for (; m + 12 < end; m += 16) {             // 4 chains in flight/group
            int s0 = sortedLoc[m],     s1 = sortedLoc[m + 4];
            int s2 = sortedLoc[m + 8], s3 = sortedLoc[m + 12];
            float e0 = edge_e(stn + ss[s0]);
            float e1 = edge_e(stn + ss[s1]);
            float e2 = edge_e(stn + ss[s2]);
            float e3 = edge_e(stn + ss[s3]);
            den += (e0 + e1) + (e2 + e3);
            uint4 p0 = *(const uint4*)(H + ((unsigned)s0 << 7) + l * 8);
            uint4 p1 = *(const uint4*)(H + ((unsigned)s1 << 7) + l * 8);
            uint4 p2 = *(const uint4*)(H + ((unsigned)s2 << 7) + l * 8);
            uint4 p3 = *(const uint4*)(H + ((unsigned)s3 << 7) + l * 8);
            float2v E0 = {e0, e0}, E1 = {e1, e1}, E2 = {e2, e2}, E3 = {e3, e3};
            acc2[0] += E0 * up2(p0.x) + E1 * up2(p1.x) + E2 * up2(p2.x) + E3 * up2(p3.x);
            acc2[1] += E0 * up2(p0.y) + E1 * up2(p1.y) + E2 * up2(p2.y) + E3 * up2(p3.y);
            acc2[2] += E0 * up2(p0.z) + E1 * up2(p1.z) + E2 * up2(p2.z) + E3 * up2(p3.z);
            acc2[3] += E0 * up2(p0.w) + E1 * up2(p1.w) + E2 * up2(p2.w) + E3 * up2(p3.w);
        }
        for (; m + 4 < end; m += 8) {               // 2-chain remainder
            int s0 = sortedLoc[m], s1 = sortedLoc[m + 4];
            float e0 = edge_e(stn + ss[s0]);
            float e1 = edge_e(stn + ss[s1]);
            den += e0 + e1;
            uint4 p0 = *(const uint4*)(H + ((unsigned)s0 << 7) + l * 8);
            uint4 p1 = *(const uint4*)(H + ((unsigned)s1 << 7) + l * 8);
            float2v E0 = {e0, e0}, E1 = {e1, e1};
            acc2[0] += E0 * up2(p0.x) + E1 * up2(p1.x);
            acc2[1] += E0 * up2(p0.y) + E1 * up2(p1.y);
            acc2[2] += E0 * up2(p0.z) + E1 * up2(p1.z);
            acc2[3] += E0 * up2(p0.w) + E1 * up2(p1.w);
        }
        if (m < end) {
            int s0 = sortedLoc[m];
            float e0 = edge_e(stn + ss[s0]);
            den += e0;
            uint4 p0 = *(const uint4*)(H + ((unsigned)s0 << 7) + l * 8);
            float2v E0 = {e0, e0};
            acc2[0] += E0 * up2(p0.x);
            acc2[1] += E0 * up2(p0.y);
            acc2[2] += E0 * up2(p0.z);
            acc2[3] += E0 * up2(p0.w);
        }
        den += __shfl_xor(den, 16);
        den += __shfl_xor(den, 32);
        float r[8];
#pragma unroll
        for (int j = 0; j < 4; j++) {
            float a0 = acc2[j].x, a1 = acc2[j].y;
            a0 += __shfl_xor(a0, 16); a0 += __shfl_xor(a0, 32);
            a1 += __shfl_xor(a1, 16); a1 += __shfl_xor(a1, 32);
            r[j * 2] = a0; r[j * 2 + 1] = a1;
        }
        float inv = 1.0f / (den + 1e-9f);
        if (g == 0) {
            // packed-pair H layout: r[k] holds logical col k*16 + l.
#pragma unroll
            for (int k = 0; k < 8; k++)
                out[(size_t)gnode * D + k * 16 + l] = r[k] * inv;
        }
    }
}

extern "C" void kernel_launch(void* const* d_in, const int* in_sizes, int n_in,
                              void* d_out, int out_size, void* d_ws, size_t ws_size,
                              hipStream_t stream) {
    const float* X  = (const float*)d_in[0];
    const int*   E  = (const int*)d_in[1];
    const float* W  = (const float*)d_in[2];
    const float* KA = (const float*)d_in[3];
    for (int i = 0; i < n_in; i++) {
        int s = in_sizes[i];
        if (s == N_NODES * D)      X  = (const float*)d_in[i];
        else if (s == N_EDGES * 2) E  = (const int*)d_in[i];
        else if (s == D * D)       W  = (const float*)d_in[i];
        else if (s == 2 * D)       KA = (const float*)d_in[i];
    }
    float* out = (float*)d_out;                // fp32 [100000,128]; no aliasing

    char* ws = (char*)d_ws;
    // workspace layout (16B aligned), total 33,583,032 B (proven in r10/r11)
    ushort_t* H        = (ushort_t*)(ws + 0);           // 25,600,000 B (bf16 h)
    float*    st       = (float*)   (ws + 25601024);    //    400,000 B
    float*    ssb      = (float*)   (ws + 26001024);    //    400,000 B
    int*      sortedE  = (int*)     (ws + 26401024);    //  6,400,000 B
    ushort_t* bmat     = (ushort_t*)(ws + 32801024);    //    391,000 B
    ushort_t* lofs     = (ushort_t*)(ws + 33192032);    //    391,000 B

    fused_kernel<<<NB_GEMM + NWIN, 256, 0, stream>>>(X, W, KA, H, st, ssb,
                                                     N_NODES, E,
                                                     sortedE, bmat, lofs);
    agg2_kernel<<<BUCKETS, 512, 0, stream>>>(bmat, lofs, sortedE, st, ssb,
                                             H, out);
}

// Round 16
// 208.563 us; speedup vs baseline: 1.1134x; 1.0892x over previous
//
#include <hip/hip_runtime.h>
#include <stdint.h>

typedef unsigned short ushort_t;
typedef __attribute__((ext_vector_type(8))) short short8;   // 8 bf16 = 4 VGPRs
typedef __attribute__((ext_vector_type(4))) float float4v;  // MFMA acc
typedef __attribute__((ext_vector_type(2))) float float2v;  // packed f32 pair

#define N_NODES 100000
#define N_EDGES 1600000
#define D 128
#define NB_GEMM 1563   // (N_NODES+63)/64 tiles of 64 rows
#define NBG     521    // gemm blocks: tiles b, b+521, b+1042 (521*3 = 1563)
#define NWIN    250    // edge windows (b1 blocks)
#define EPB     6400   // edges per window: 250*6400 = 1,600,000 = 25*256 each
#define BUCKETS 782    // ceil(100000/128), 128 nodes per bucket
#define CAP     2560   // per-bucket edge cap (mean 2046, sd 45 -> 11 sigma)

static __device__ __forceinline__ float2v up2(uint32_t u) {  // 2 bf16 -> 2 f32
    float2v r;
    r.x = __builtin_bit_cast(float, u << 16);
    r.y = __builtin_bit_cast(float, u & 0xffff0000u);
    return r;
}
static __device__ __forceinline__ uint32_t f2bf_u(float f) {
    uint32_t u = __builtin_bit_cast(uint32_t, f);
    return (u + 0x7fffu + ((u >> 16) & 1u)) >> 16;           // RNE
}
static __device__ __forceinline__ ushort_t f2bf(float f) {
    return (ushort_t)f2bf_u(f);
}
static __device__ __forceinline__ uint32_t pack2(float a, float b) {
    return f2bf_u(a) | (f2bf_u(b) << 16);
}
// leaky_relu(0.2) -> clip(-2,2) -> exp
static __device__ __forceinline__ float edge_e(float s) {
    float x = (s >= 0.0f) ? s : 0.2f * s;
    x = fminf(fmaxf(x, -2.0f), 2.0f);
    return __expf(x);
}

// ---------------- fused: [0..520] gemm (3 tiles, conflict-free W+wa staging) -
//                  [521..770] b1 bucket sort (reg-cached, 1 E read) -----------
// H row layout is PACKED-PAIR order: element l16*8+2j+hi <-> col (2j+hi)*16+l16.
__global__ void __launch_bounds__(256) fused_kernel(const float* __restrict__ X,
                                                    const float* __restrict__ W,
                                                    const float* __restrict__ KA,
                                                    ushort_t* __restrict__ H,
                                                    float* __restrict__ st,
                                                    float* __restrict__ ss,
                                                    int M,
                                                    const int* __restrict__ E,
                                                    int* __restrict__ sortedE,
                                                    ushort_t* __restrict__ bmat,
                                                    ushort_t* __restrict__ lofs) {
    __shared__ __align__(16) ushort_t lds_raw[16384];   // 32 KB, both branches
    __shared__ float lds_wa[256];                       // gemm: W @ ka (exact)
    __shared__ int   ldet;                              // b1: dtype verdict
    int tid = threadIdx.x;
    if (blockIdx.x >= NBG) {
        // ------------- b1: bucket-sort 6400 edges by tgt>>7, LDS atomics only
        int eb = blockIdx.x - NBG;
        int* lhist = (int*)lds_raw;                 // [1024] (782 used)
        int* lpart = ((int*)lds_raw) + 1024;        // [256]
        int t = tid;
        // self-detect edge dtype from first 2048 edges (identical all blocks)
        if (t == 0) ldet = 0;
        for (int j = t; j < 1024; j += 256) lhist[j] = 0;
        __syncthreads();
        int nz = 0;
#pragma unroll
        for (int j = 0; j < 8; j++)
            if (E[(t + j * 256) * 2 + 1] != 0) nz = 1;
        if (nz) atomicOr(&ldet, 1);
        __syncthreads();
        int i64 = (ldet == 0) ? 1 : 0;              // block-uniform
        int base = eb * EPB;
        int bin[25], w[25];                         // static-indexed (unrolled)
#pragma unroll
        for (int j = 0; j < 25; j++) {
            int i = base + j * 256 + t;
            int tgt, src;
            if (i64) { uint4 v = *(const uint4*)(E + (size_t)i * 4); tgt = (int)v.x; src = (int)v.z; }
            else     { uint2 v = *(const uint2*)(E + (size_t)i * 2); tgt = (int)v.x; src = (int)v.y; }
            if ((unsigned)tgt >= (unsigned)N_NODES) tgt = 0;
            if ((unsigned)src >= (unsigned)N_NODES) src = 0;
            bin[j] = tgt >> 7;
            w[j]   = ((tgt & 127) << 17) | src;
            atomicAdd(&lhist[bin[j]], 1);
        }
        __syncthreads();
        // per-thread 4 bins -> block scan
        int c0 = lhist[t * 4], c1 = lhist[t * 4 + 1];
        int c2 = lhist[t * 4 + 2], c3 = lhist[t * 4 + 3];
        int sum = c0 + c1 + c2 + c3;
        lpart[t] = sum;
        __syncthreads();
        for (int off = 1; off < 256; off <<= 1) {   // Hillis-Steele inclusive
            int x = (t >= off) ? lpart[t - off] : 0;
            __syncthreads();
            lpart[t] += x;
            __syncthreads();
        }
        int e0 = lpart[t] - sum;                    // exclusive base of bin 4t
        int e1 = e0 + c0, e2 = e1 + c1, e3 = e2 + c2;
        int cc[4] = {c0, c1, c2, c3};
        int ee[4] = {e0, e1, e2, e3};
#pragma unroll
        for (int k = 0; k < 4; k++) {
            int bb = t * 4 + k;
            if (bb < BUCKETS) {
                bmat[eb * BUCKETS + bb] = (ushort_t)cc[k];
                lofs[eb * BUCKETS + bb] = (ushort_t)ee[k];
            }
        }
        // lhist becomes the placement cursor (own slots, no cross-thread reads)
        lhist[t * 4] = e0; lhist[t * 4 + 1] = e1;
        lhist[t * 4 + 2] = e2; lhist[t * 4 + 3] = e3;
        __syncthreads();
        // pass 2 entirely from registers
#pragma unroll
        for (int j = 0; j < 25; j++) {
            int pos = atomicAdd(&lhist[bin[j]], 1);
            if (pos < EPB) sortedE[base + pos] = w[j];
        }
        return;
    }
    // -------- gemm branch: conflict-free W staging (short8 per thread) ------
    {
        // task c -> (kb,tt,q,l): writes ONE contiguous 16B group (8 consec k)
        for (int c = tid; c < 2048; c += 256) {
            int l = c & 15, q = (c >> 4) & 3, tt = (c >> 6) & 7, kb = c >> 9;
            int n = tt * 16 + l;
            int k0 = kb * 32 + q * 8;
            short8 v;
#pragma unroll
            for (int jj = 0; jj < 8; jj++)
                v[jj] = (short)f2bf(W[(size_t)(k0 + jj) * 128 + n]);
            *(short8*)(&lds_raw[((kb * 8 + tt) * 64 + q * 16 + l) * 8]) = v;
        }
        // wa[half*128+k] = dot(W row k, KA col half) -- fp32, float4 loads
        int half = tid >> 7, k = tid & 127;
        const float4* kav4  = (const float4*)(KA + half * 128);
        const float4* wrow4 = (const float4*)(W + (size_t)k * 128);
        float acc = 0.0f;
#pragma unroll 8
        for (int j = 0; j < 32; j++) {
            float4 a4 = wrow4[j], b4 = kav4[j];
            acc += a4.x * b4.x + a4.y * b4.y + a4.z * b4.z + a4.w * b4.w;
        }
        lds_wa[half * 128 + k] = acc;
    }
    __syncthreads();

    int wave = tid >> 6, lane = tid & 63;
    int quad = lane >> 4, l16 = lane & 15;
    int t0 = blockIdx.x;

    float4 f[8];                                    // current tile X (A rows)
    {
        int ar = t0 * 64 + wave * 16 + l16; if (ar >= M) ar = M - 1;
        const float* xr = X + (size_t)ar * D + quad * 8;
#pragma unroll
        for (int kb = 0; kb < 4; kb++) {
            f[kb * 2]     = *(const float4*)(xr + kb * 32);
            f[kb * 2 + 1] = *(const float4*)(xr + kb * 32 + 4);
        }
    }
#pragma unroll
    for (int it = 0; it < 3; it++) {                // tiles t0, t0+521, t0+1042
        int m0 = (t0 + it * NBG) * 64 + wave * 16;
        float4 nf[8];
        if (it < 2) {                               // prefetch next tile's X
            int ar = (t0 + (it + 1) * NBG) * 64 + wave * 16 + l16;
            if (ar >= M) ar = M - 1;
            const float* xr = X + (size_t)ar * D + quad * 8;
#pragma unroll
            for (int kb = 0; kb < 4; kb++) {
                nf[kb * 2]     = *(const float4*)(xr + kb * 32);
                nf[kb * 2 + 1] = *(const float4*)(xr + kb * 32 + 4);
            }
        }
        // fused scores (fp32) + bf16 cvt
        short8 a[4];
        float sct = 0.0f, scs = 0.0f;
#pragma unroll
        for (int kb = 0; kb < 4; kb++) {            // A[m=l16][k=kb*32+quad*8+j]
            float4 f0 = f[kb * 2], f1 = f[kb * 2 + 1];
            const float* wt0 = lds_wa + kb * 32 + quad * 8;
            float4 t0v = *(const float4*)(wt0);
            float4 t1v = *(const float4*)(wt0 + 4);
            float4 s0v = *(const float4*)(wt0 + 128);
            float4 s1v = *(const float4*)(wt0 + 132);
            sct += f0.x * t0v.x + f0.y * t0v.y + f0.z * t0v.z + f0.w * t0v.w
                 + f1.x * t1v.x + f1.y * t1v.y + f1.z * t1v.z + f1.w * t1v.w;
            scs += f0.x * s0v.x + f0.y * s0v.y + f0.z * s0v.z + f0.w * s0v.w
                 + f1.x * s1v.x + f1.y * s1v.y + f1.z * s1v.z + f1.w * s1v.w;
            short8 v;
            v[0] = (short)f2bf(f0.x); v[1] = (short)f2bf(f0.y);
            v[2] = (short)f2bf(f0.z); v[3] = (short)f2bf(f0.w);
            v[4] = (short)f2bf(f1.x); v[5] = (short)f2bf(f1.y);
            v[6] = (short)f2bf(f1.z); v[7] = (short)f2bf(f1.w);
            a[kb] = v;
        }
        sct += __shfl_xor(sct, 16); sct += __shfl_xor(sct, 32);
        scs += __shfl_xor(scs, 16); scs += __shfl_xor(scs, 32);
        if (quad == 0 && m0 + l16 < M) { st[m0 + l16] = sct; ss[m0 + l16] = scs; }

        float4v acc[8] = {};
#pragma unroll
        for (int kb = 0; kb < 4; kb++) {
#pragma unroll
            for (int t = 0; t < 8; t++) {           // B[k=kb*32+quad*8+j][n=t*16+l16]
                short8 b = *(const short8*)(&lds_raw[((kb * 8 + t) * 64 + lane) * 8]);
                acc[t] = __builtin_amdgcn_mfma_f32_16x16x32_bf16(a[kb], b, acc[t], 0, 0, 0);
            }
        }
        // C/D: col = t*16 + l16, row = quad*4 + r   [m89-verified]
#pragma unroll
        for (int r = 0; r < 4; r++) {
            int orow = m0 + quad * 4 + r;
            if (orow < M) {
                uint4 v;
                v.x = pack2(acc[0][r], acc[1][r]);
                v.y = pack2(acc[2][r], acc[3][r]);
                v.z = pack2(acc[4][r], acc[5][r]);
                v.w = pack2(acc[6][r], acc[7][r]);
                *(uint4*)(H + (size_t)orow * D + l16 * 8) = v;
            }
        }
        if (it < 2) {
#pragma unroll
            for (int j = 0; j < 8; j++) f[j] = nf[j];
        }
    }
}

// ---------------- agg2: fused CSR-build + aggregation, 1 block = 1 bucket ----
// Phase A: shfl-scan; FLAT coalesced gather via binary search; hist+scan+place.
// Phase B: 8 waves x 16 nodes, 4 edge-slot groups/wave, unroll-4 gather of H.
__global__ void __launch_bounds__(512) agg2_kernel(const ushort_t* __restrict__ bmat,
                                                   const ushort_t* __restrict__ lofs,
                                                   const int* __restrict__ sortedE,
                                                   const float* __restrict__ st,
                                                   const float* __restrict__ ss,
                                                   const ushort_t* __restrict__ H,
                                                   float* __restrict__ out) {
    __shared__ int stage[CAP];
    __shared__ int sortedLoc[CAP];
    __shared__ int lh[128];
    __shared__ int lrp[129];
    __shared__ int wsum[8];
    __shared__ int lsoff[NWIN];
    __shared__ int lsst[NWIN];
    int b = blockIdx.x, t = threadIdx.x;
    int lane = t & 63, wv = t >> 6;
    // ---- Phase A1: exclusive scan of 250 window counts (shfl) --------------
    int cnt = 0, sst = 0;
    if (t < NWIN) {
        cnt = bmat[t * BUCKETS + b];
        sst = lofs[t * BUCKETS + b];
    }
    int x = cnt;
#pragma unroll
    for (int off = 1; off < 64; off <<= 1) {        // wave inclusive scan
        int y = __shfl_up(x, off);
        if (lane >= off) x += y;
    }
    if (lane == 63) wsum[wv] = x;
    if (t < 128) lh[t] = 0;
    __syncthreads();
    int wbase = 0, total = 0;
#pragma unroll
    for (int w = 0; w < 8; w++) {
        int sv = wsum[w];
        if (w < wv) wbase += sv;
        total += sv;
    }
    if (total > CAP) total = CAP;                   // 11-sigma guard
    int soff = wbase + x - cnt;                     // staging offset (exclusive)
    if (t < NWIN) { lsoff[t] = soff; lsst[t] = sst; }
    __syncthreads();
    // ---- flat coalesced gather: thread j pulls stage[j] --------------------
    for (int j = t; j < total; j += 512) {
        int lo = 0, hi = NWIN - 1;                  // largest w: lsoff[w] <= j
        while (lo < hi) {
            int mid = (lo + hi + 1) >> 1;
            if (lsoff[mid] <= j) lo = mid; else hi = mid - 1;
        }
        stage[j] = sortedE[lo * EPB + lsst[lo] + (j - lsoff[lo])];
    }
    __syncthreads();
    // ---- Phase A2: histogram over 128 local nodes --------------------------
    for (int j = t; j < total; j += 512)
        atomicAdd(&lh[stage[j] >> 17], 1);
    __syncthreads();
    // ---- Phase A3: scan hist -> local rowp (shfl over waves 0-1) -----------
    int v = (t < 128) ? lh[t] : 0;
    int xs = v;
#pragma unroll
    for (int off = 1; off < 64; off <<= 1) {
        int y = __shfl_up(xs, off);
        if (lane >= off) xs += y;
    }
    if (t == 63) wsum[0] = xs;                      // wave0 total
    __syncthreads();
    if (t < 128) {
        int inc = (wv == 1) ? xs + wsum[0] : xs;
        int ex = inc - v;
        lrp[t] = ex;
        lh[t]  = ex;                                // placement cursor
    }
    if (t == 0) lrp[128] = total;
    __syncthreads();
    for (int j = t; j < total; j += 512) {          // place sorted-by-node
        int p = stage[j];
        int pos = atomicAdd(&lh[p >> 17], 1);
        if (pos < total) sortedLoc[pos] = p & 0x1FFFF;
    }
    __syncthreads();
    // ---------------- Phase B: aggregate from LDS-sorted edges --------------
    int g = lane >> 4, l = lane & 15;
    for (int nd = wv; nd < 128; nd += 8) {
        int gnode = b * 128 + nd;
        if (gnode >= N_NODES) break;                // only bucket 781 tail
        int start = lrp[nd], end = lrp[nd + 1];
        float stn = st[gnode];
        float den = 0.0f;
        float2v acc2[4] = {};
        int m = start + g;
        for (; m + 12 < end; m += 16) {             // 4 chains in flight/group
            int s0 = sortedLoc[m],     s1 = sortedLoc[m + 4];
            int s2 = sortedLoc[m + 8], s3 = sortedLoc[m + 12];
            float e0 = edge_e(stn + ss[s0]);
            float e1 = edge_e(stn + ss[s1]);
            float e2 = edge_e(stn + ss[s2]);
            float e3 = edge_e(stn + ss[s3]);
            den += (e0 + e1) + (e2 + e3);
            uint4 p0 = *(const uint4*)(H + ((unsigned)s0 << 7) + l * 8);
            uint4 p1 = *(const uint4*)(H + ((unsigned)s1 << 7) + l * 8);
            uint4 p2 = *(const uint4*)(H + ((unsigned)s2 << 7) + l * 8);
            uint4 p3 = *(const uint4*)(H + ((unsigned)s3 << 7) + l * 8);
            float2v E0 = {e0, e0}, E1 = {e1, e1}, E2 = {e2, e2}, E3 = {e3, e3};
            acc2[0] += E0 * up2(p0.x) + E1 * up2(p1.x) + E2 * up2(p2.x) + E3 * up2(p3.x);
            acc2[1] += E0 * up2(p0.y) + E1 * up2(p1.y) + E2 * up2(p2.y) + E3 * up2(p3.y);
            acc2[2] += E0 * up2(p0.z) + E1 * up2(p1.z) + E2 * up2(p2.z) + E3 * up2(p3.z);
            acc2[3] += E0 * up2(p0.w) + E1 * up2(p1.w) + E2 * up2(p2.w) + E3 * up2(p3.w);
        }
        for (; m + 4 < end; m += 8) {               // 2-chain remainder
            int s0 = sortedLoc[m], s1 = sortedLoc[m + 4];
            float e0 = edge_e(stn + ss[s0]);
            float e1 = edge_e(stn + ss[s1]);
            den += e0 + e1;
            uint4 p0 = *(const uint4*)(H + ((unsigned)s0 << 7) + l * 8);
            uint4 p1 = *(const uint4*)(H + ((unsigned)s1 << 7) + l * 8);
            float2v E0 = {e0, e0}, E1 = {e1, e1};
            acc2[0] += E0 * up2(p0.x) + E1 * up2(p1.x);
            acc2[1] += E0 * up2(p0.y) + E1 * up2(p1.y);
            acc2[2] += E0 * up2(p0.z) + E1 * up2(p1.z);
            acc2[3] += E0 * up2(p0.w) + E1 * up2(p1.w);
        }
        if (m < end) {
            int s0 = sortedLoc[m];
            float e0 = edge_e(stn + ss[s0]);
            den += e0;
            uint4 p0 = *(const uint4*)(H + ((unsigned)s0 << 7) + l * 8);
            float2v E0 = {e0, e0};
            acc2[0] += E0 * up2(p0.x);
            acc2[1] += E0 * up2(p0.y);
            acc2[2] += E0 * up2(p0.z);
            acc2[3] += E0 * up2(p0.w);
        }
        den += __shfl_xor(den, 16);
        den += __shfl_xor(den, 32);
        float r[8];
#pragma unroll
        for (int j = 0; j < 4; j++) {
            float a0 = acc2[j].x, a1 = acc2[j].y;
            a0 += __shfl_xor(a0, 16); a0 += __shfl_xor(a0, 32);
            a1 += __shfl_xor(a1, 16); a1 += __shfl_xor(a1, 32);
            r[j * 2] = a0; r[j * 2 + 1] = a1;
        }
        float inv = 1.0f / (den + 1e-9f);
        if (g == 0) {
            // packed-pair H layout: r[k] holds logical col k*16 + l.
#pragma unroll
            for (int k = 0; k < 8; k++)
                out[(size_t)gnode * D + k * 16 + l] = r[k] * inv;
        }
    }
}

extern "C" void kernel_launch(void* const* d_in, const int* in_sizes, int n_in,
                              void* d_out, int out_size, void* d_ws, size_t ws_size,
                              hipStream_t stream) {
    const float* X  = (const float*)d_in[0];
    const int*   E  = (const int*)d_in[1];
    const float* W  = (const float*)d_in[2];
    const float* KA = (const float*)d_in[3];
    for (int i = 0; i < n_in; i++) {
        int s = in_sizes[i];
        if (s == N_NODES * D)      X  = (const float*)d_in[i];
        else if (s == N_EDGES * 2) E  = (const int*)d_in[i];
        else if (s == D * D)       W  = (const float*)d_in[i];
        else if (s == 2 * D)       KA = (const float*)d_in[i];
    }
    float* out = (float*)d_out;                // fp32 [100000,128]; no aliasing

    char* ws = (char*)d_ws;
    // workspace layout (16B aligned), total 33,583,032 B (proven in r10/r11)
    ushort_t* H        = (ushort_t*)(ws + 0);           // 25,600,000 B (bf16 h)
    float*    st       = (float*)   (ws + 25601024);    //    400,000 B
    float*    ssb      = (float*)   (ws + 26001024);    //    400,000 B
    int*      sortedE  = (int*)     (ws + 26401024);    //  6,400,000 B
    ushort_t* bmat     = (ushort_t*)(ws + 32801024);    //    391,000 B
    ushort_t* lofs     = (ushort_t*)(ws + 33192032);    //    391,000 B

    fused_kernel<<<NBG + NWIN, 256, 0, stream>>>(X, W, KA, H, st, ssb,
                                                 N_NODES, E,
                                                 sortedE, bmat, lofs);
    agg2_kernel<<<BUCKETS, 512, 0, stream>>>(bmat, lofs, sortedE, st, ssb,
                                             H, out);
}